// Round 1
// baseline (308.055 us; speedup 1.0000x reference)
//
#include <hip/hip_runtime.h>

// RoI Align, ALIGNED=False, SCALE=160.
// feat: (N=8, C=256, H=160, W=160) fp32
// rois: (K, 5) fp32  [b, x1, y1, x2, y2] in [0,1]
// out:  (K, C, OH=14, OW=14) fp32
//
// ALIGNED=False math simplifies: ix = x1*W_s + gx*(x2-x1)*W_s - 0.5
// (the normalize/denormalize round-trip is exactly fx - 0.5).

#define FM_N 8
#define FM_C 256
#define FM_H 160
#define FM_W 160
#define OH 14
#define OW 14
#define OSP (OH * OW)   // 196 spatial outputs per (k,c)
#define CPB 64          // channels per block
#define SCALE_HW 160.0f

__global__ __launch_bounds__(256) void roi_align_kernel(
    const float* __restrict__ feat,
    const float* __restrict__ rois,
    float* __restrict__ out) {
  const int k = blockIdx.x;
  const int cbase = blockIdx.y * CPB;
  const int s = threadIdx.x;

  // ROI params (wave-uniform broadcast loads)
  const float rb = rois[k * 5 + 0];
  const float x1 = rois[k * 5 + 1] * SCALE_HW;
  const float y1 = rois[k * 5 + 2] * SCALE_HW;
  const float x2 = rois[k * 5 + 3] * SCALE_HW;
  const float y2 = rois[k * 5 + 4] * SCALE_HW;
  const int b = (int)rb;

  if (s >= OSP) return;  // lanes 196..255 idle (memory-bound; acceptable)

  const int oy = s / OW;
  const int ox = s - oy * OW;
  const float gx = (float)ox * (1.0f / (OW - 1));
  const float gy = (float)oy * (1.0f / (OH - 1));

  // ALIGNED=False: ix = fx - 0.5
  const float ix = x1 + gx * (x2 - x1) - 0.5f;
  const float iy = y1 + gy * (y2 - y1) - 0.5f;

  const float fx0 = floorf(ix);
  const float fy0 = floorf(iy);
  const int x0 = (int)fx0;
  const int y0 = (int)fy0;
  const float wx1 = ix - fx0;
  const float wy1 = iy - fy0;
  const float wx0 = 1.0f - wx1;
  const float wy0 = 1.0f - wy1;

  const float vx0 = (x0 >= 0 && x0 < FM_W) ? 1.0f : 0.0f;
  const float vx1 = (x0 + 1 >= 0 && x0 + 1 < FM_W) ? 1.0f : 0.0f;
  const float vy0 = (y0 >= 0 && y0 < FM_H) ? 1.0f : 0.0f;
  const float vy1 = (y0 + 1 >= 0 && y0 + 1 < FM_H) ? 1.0f : 0.0f;

  const int x0c = min(max(x0, 0), FM_W - 1);
  const int x1c = min(max(x0 + 1, 0), FM_W - 1);
  const int y0c = min(max(y0, 0), FM_H - 1);
  const int y1c = min(max(y0 + 1, 0), FM_H - 1);

  const int o00 = y0c * FM_W + x0c;
  const int o01 = y0c * FM_W + x1c;
  const int o10 = y1c * FM_W + x0c;
  const int o11 = y1c * FM_W + x1c;

  const float w00 = wy0 * wx0 * vy0 * vx0;
  const float w01 = wy0 * wx1 * vy0 * vx1;
  const float w10 = wy1 * wx0 * vy1 * vx0;
  const float w11 = wy1 * wx1 * vy1 * vx1;

  const float* __restrict__ plane =
      feat + ((size_t)b * FM_C + cbase) * (FM_H * FM_W);
  float* __restrict__ outp = out + ((size_t)k * FM_C + cbase) * OSP + s;

#pragma unroll 4
  for (int c = 0; c < CPB; ++c) {
    const float* __restrict__ p = plane + (size_t)c * (FM_H * FM_W);
    const float v = w00 * p[o00] + w01 * p[o01] + w10 * p[o10] + w11 * p[o11];
    outp[c * OSP] = v;
  }
}

extern "C" void kernel_launch(void* const* d_in, const int* in_sizes, int n_in,
                              void* d_out, int out_size, void* d_ws, size_t ws_size,
                              hipStream_t stream) {
  const float* feat = (const float*)d_in[0];
  const float* rois = (const float*)d_in[1];
  float* out = (float*)d_out;

  const int K = in_sizes[1] / 5;  // 1024

  dim3 grid(K, FM_C / CPB, 1);    // (1024, 4)
  dim3 block(256, 1, 1);
  roi_align_kernel<<<grid, block, 0, stream>>>(feat, rois, out);
}

// Round 2
// 168.069 us; speedup vs baseline: 1.8329x; 1.8329x over previous
//
#include <hip/hip_runtime.h>
#include <hip/hip_fp16.h>

// RoI Align, ALIGNED=False, SCALE=160 — LDS-staged, one plane read per (b,c).
// feat: (N=8, C=256, H=160, W=160) fp32
// rois: (K=1024, 5) fp32 [b, x1, y1, x2, y2] in [0,1]
// out:  (K, C, 14, 14) fp32
//
// ALIGNED=False index math collapses to ix = fx - 0.5.

#define FM_N 8
#define FM_C 256
#define FM_H 160
#define FM_W 160
#define PLANE (FM_H * FM_W)   // 25600
#define OH 14
#define OW 14
#define OSP (OH * OW)         // 196
#define KMAX 1024
#define SCALE_HW 160.0f

// ws layout (ints): cnt[8] | pad to 16 | list[8][KMAX]
#define WS_LIST_OFF 16

// Build per-batch ROI lists. One block. List order is irrelevant to the
// final output (each k writes only its own rows), so LDS-atomic append is
// deterministic-output-safe. cnt is freshly computed every launch.
__global__ void build_lists_kernel(const float* __restrict__ rois, int K,
                                   int* __restrict__ ws) {
  __shared__ int cnt[FM_N];
  const int t = threadIdx.x;
  if (t < FM_N) cnt[t] = 0;
  __syncthreads();
  for (int k = t; k < K; k += blockDim.x) {
    const int b = (int)rois[k * 5];
    const int pos = atomicAdd(&cnt[b], 1);
    ws[WS_LIST_OFF + b * KMAX + pos] = k;
  }
  __syncthreads();
  if (t < FM_N) ws[t] = cnt[t];
}

__global__ __launch_bounds__(256) void roi_align_lds_kernel(
    const float* __restrict__ feat,
    const float* __restrict__ rois,
    const int* __restrict__ ws,
    float* __restrict__ out) {
  __shared__ __align__(16) __half plane[PLANE];

  const int bid = blockIdx.x;
  const int c = bid & (FM_C - 1);
  const int b = bid >> 8;
  const int t = threadIdx.x;

  // ---- stage plane (b,c): 102.4 KB fp32 -> 51.2 KB fp16 in LDS, coalesced
  const float4* __restrict__ src =
      (const float4*)(feat + ((size_t)b * FM_C + c) * PLANE);
#pragma unroll
  for (int i = 0; i < PLANE / 4 / 256; ++i) {  // 25 iterations
    const float4 v = src[t + i * 256];
    __half2* dst = (__half2*)&plane[4 * (t + i * 256)];
    dst[0] = __floats2half2_rn(v.x, v.y);
    dst[1] = __floats2half2_rn(v.z, v.w);
  }
  __syncthreads();

  // ---- all ROIs of batch b, flattened over (k_local, s)
  const int cnt = ws[b];
  const int* __restrict__ list = ws + WS_LIST_OFF + b * KMAX;
  const int total = cnt * OSP;

  for (int w = t; w < total; w += 256) {
    const unsigned kl = (unsigned)w / OSP;
    const int s = w - (int)kl * OSP;
    const int k = list[kl];

    const float x1 = rois[k * 5 + 1] * SCALE_HW;
    const float y1 = rois[k * 5 + 2] * SCALE_HW;
    const float x2 = rois[k * 5 + 3] * SCALE_HW;
    const float y2 = rois[k * 5 + 4] * SCALE_HW;

    const int oy = s / OW;
    const int ox = s - oy * OW;
    const float gx = (float)ox * (1.0f / (OW - 1));
    const float gy = (float)oy * (1.0f / (OH - 1));

    const float ix = x1 + gx * (x2 - x1) - 0.5f;
    const float iy = y1 + gy * (y2 - y1) - 0.5f;

    const float fx0 = floorf(ix);
    const float fy0 = floorf(iy);
    const int x0 = (int)fx0;
    const int y0 = (int)fy0;
    const float wx1 = ix - fx0;
    const float wy1 = iy - fy0;
    const float wx0 = 1.0f - wx1;
    const float wy0 = 1.0f - wy1;

    const float vx0 = (x0 >= 0 && x0 < FM_W) ? 1.0f : 0.0f;
    const float vx1 = (x0 + 1 >= 0 && x0 + 1 < FM_W) ? 1.0f : 0.0f;
    const float vy0 = (y0 >= 0 && y0 < FM_H) ? 1.0f : 0.0f;
    const float vy1 = (y0 + 1 >= 0 && y0 + 1 < FM_H) ? 1.0f : 0.0f;

    const int x0c = min(max(x0, 0), FM_W - 1);
    const int x1c = min(max(x0 + 1, 0), FM_W - 1);
    const int y0c = min(max(y0, 0), FM_H - 1);
    const int y1c = min(max(y0 + 1, 0), FM_H - 1);

    const float p00 = __half2float(plane[y0c * FM_W + x0c]);
    const float p01 = __half2float(plane[y0c * FM_W + x1c]);
    const float p10 = __half2float(plane[y1c * FM_W + x0c]);
    const float p11 = __half2float(plane[y1c * FM_W + x1c]);

    const float v = (wy0 * wx0 * vy0 * vx0) * p00 +
                    (wy0 * wx1 * vy0 * vx1) * p01 +
                    (wy1 * wx0 * vy1 * vx0) * p10 +
                    (wy1 * wx1 * vy1 * vx1) * p11;

    out[((size_t)k * FM_C + c) * OSP + s] = v;
  }
}

extern "C" void kernel_launch(void* const* d_in, const int* in_sizes, int n_in,
                              void* d_out, int out_size, void* d_ws, size_t ws_size,
                              hipStream_t stream) {
  const float* feat = (const float*)d_in[0];
  const float* rois = (const float*)d_in[1];
  float* out = (float*)d_out;
  int* ws = (int*)d_ws;

  const int K = in_sizes[1] / 5;  // 1024

  build_lists_kernel<<<1, 1024, 0, stream>>>(rois, K, ws);
  roi_align_lds_kernel<<<FM_N * FM_C, 256, 0, stream>>>(feat, rois, ws, out);
}

// Round 3
// 138.967 us; speedup vs baseline: 2.2167x; 1.2094x over previous
//
#include <hip/hip_runtime.h>
#include <hip/hip_fp16.h>

// RoI Align, ALIGNED=False, SCALE=160.
// feat: (N=8, C=256, H=160, W=160) fp32
// rois: (K=1024, 5) fp32 [b, x1, y1, x2, y2]
// out:  (K, C, 14, 14) fp32
//
// Structure:
//  A) setup_kernel: per-batch counts + batch-grouped slot for each k.
//  B) precompute_kernel: per-(k,s) sample descriptor {pack, outbase, ax, ay}
//     (weights identical across channels -> computed ONCE, not 256x).
//  C) main kernel: one block per (b,c); stage fp16 plane in LDS; iterate
//     batch-b samples: uint4 load + 4 ds_read_u16 + 6 FMA + store.

#define FM_N 8
#define FM_C 256
#define FM_H 160
#define FM_W 160
#define PLANE (FM_H * FM_W)   // 25600
#define OH 14
#define OW 14
#define OSP (OH * OW)         // 196
#define KMAX 1024
#define SCALE_HW 160.0f
#define MAIN_BLK 512

// ws layout (int32 units):
//   [0..7]    cnt[b]
//   [8..15]   koff[b]  (exclusive prefix sum of cnt, in k units)
//   [16..16+K) slot[k] (batch-grouped position of roi k, in k units)
//   byte 4160: samples[K*196] as uint4 {pack, outbase, ax(half2), ay(half2)}
#define WS_SLOT_OFF 16
#define WS_SAMPLES_BYTE_OFF 4160

__global__ void setup_kernel(const float* __restrict__ rois, int K,
                             int* __restrict__ ws) {
  __shared__ int cnt[FM_N];
  __shared__ int koff[FM_N];
  const int t = threadIdx.x;
  if (t < FM_N) cnt[t] = 0;
  __syncthreads();
  int myb = -1, pos = 0;
  if (t < K) {
    myb = (int)rois[t * 5];
    pos = atomicAdd(&cnt[myb], 1);  // rank order irrelevant: each sample
                                    // writes a unique output location
  }
  __syncthreads();
  if (t == 0) {
    int acc = 0;
    for (int b = 0; b < FM_N; ++b) { koff[b] = acc; acc += cnt[b]; }
  }
  __syncthreads();
  if (t < K) ws[WS_SLOT_OFF + t] = koff[myb] + pos;
  if (t < FM_N) { ws[t] = cnt[t]; ws[FM_N + t] = koff[t]; }
}

__global__ __launch_bounds__(256) void precompute_kernel(
    const float* __restrict__ rois, const int* __restrict__ ws, int K,
    uint4* __restrict__ samples) {
  const int g = blockIdx.x * 256 + threadIdx.x;
  if (g >= K * OSP) return;
  const int k = g / OSP;
  const int s = g - k * OSP;

  const float x1 = rois[k * 5 + 1] * SCALE_HW;
  const float y1 = rois[k * 5 + 2] * SCALE_HW;
  const float x2 = rois[k * 5 + 3] * SCALE_HW;
  const float y2 = rois[k * 5 + 4] * SCALE_HW;

  const int oy = s / OW;
  const int ox = s - oy * OW;
  const float gx = (float)ox * (1.0f / (OW - 1));
  const float gy = (float)oy * (1.0f / (OH - 1));

  // ALIGNED=False index math collapses to ix = fx - 0.5
  const float ix = x1 + gx * (x2 - x1) - 0.5f;
  const float iy = y1 + gy * (y2 - y1) - 0.5f;

  const float fx0 = floorf(ix);
  const float fy0 = floorf(iy);
  const int x0 = (int)fx0;
  const int y0 = (int)fy0;
  const float wx1 = ix - fx0;
  const float wy1 = iy - fy0;
  const float wx0 = 1.0f - wx1;
  const float wy0 = 1.0f - wy1;

  const float vx0 = (x0 >= 0 && x0 < FM_W) ? 1.0f : 0.0f;
  const float vx1 = (x0 + 1 >= 0 && x0 + 1 < FM_W) ? 1.0f : 0.0f;
  const float vy0 = (y0 >= 0 && y0 < FM_H) ? 1.0f : 0.0f;
  const float vy1 = (y0 + 1 >= 0 && y0 + 1 < FM_H) ? 1.0f : 0.0f;

  const int x0c = min(max(x0, 0), FM_W - 1);
  const int x1c = min(max(x0 + 1, 0), FM_W - 1);
  const int y0c = min(max(y0, 0), FM_H - 1);
  const int y1c = min(max(y0 + 1, 0), FM_H - 1);

  const unsigned o00 = (unsigned)(y0c * FM_W + x0c);      // < 25600, 15 bits
  const unsigned dx = (unsigned)(x1c - x0c);              // 0 or 1
  const unsigned dyf = (unsigned)(y1c - y0c);             // 0 or 1
  const unsigned pack = o00 | (dx << 15) | (dyf << 16);

  const __half2 axh = __floats2half2_rn(wx0 * vx0, wx1 * vx1);
  const __half2 ayh = __floats2half2_rn(wy0 * vy0, wy1 * vy1);

  uint4 sd;
  sd.x = pack;
  sd.y = (unsigned)(k * (OSP * FM_C) + s);  // out index = outbase + c*OSP
  sd.z = *(const unsigned*)&axh;
  sd.w = *(const unsigned*)&ayh;

  const int slot = ws[WS_SLOT_OFF + k];
  samples[(size_t)slot * OSP + s] = sd;
}

__global__ __launch_bounds__(MAIN_BLK) void roi_align_main_kernel(
    const float* __restrict__ feat, const int* __restrict__ ws,
    const uint4* __restrict__ samples, float* __restrict__ out) {
  __shared__ __align__(16) __half plane[PLANE];

  const int bid = blockIdx.x;
  const int c = bid & (FM_C - 1);
  const int b = bid >> 8;
  const int t = threadIdx.x;

  // stage plane (b,c): fp32 -> fp16 LDS, coalesced float4 loads
  const float4* __restrict__ src =
      (const float4*)(feat + ((size_t)b * FM_C + c) * PLANE);
  for (int i = t; i < PLANE / 4; i += MAIN_BLK) {
    const float4 v = src[i];
    __half2* dst = (__half2*)&plane[4 * i];
    dst[0] = __floats2half2_rn(v.x, v.y);
    dst[1] = __floats2half2_rn(v.z, v.w);
  }

  const int cnt = ws[b];
  const int koff = ws[FM_N + b];
  const uint4* __restrict__ sam = samples + (size_t)koff * OSP;
  float* __restrict__ outc = out + (size_t)c * OSP;
  __syncthreads();

  const int total = cnt * OSP;
  for (int w = t; w < total; w += MAIN_BLK) {
    const uint4 sd = sam[w];
    const int o00 = (int)(sd.x & 0x7FFFu);
    const int dx = (int)((sd.x >> 15) & 1u);
    const int o10 = o00 + (int)((sd.x >> 16) & 1u) * FM_W;

    const float p00 = __half2float(plane[o00]);
    const float p01 = __half2float(plane[o00 + dx]);
    const float p10 = __half2float(plane[o10]);
    const float p11 = __half2float(plane[o10 + dx]);

    const __half2 ax = *(const __half2*)&sd.z;
    const __half2 ay = *(const __half2*)&sd.w;
    const float ax0 = __low2float(ax), ax1 = __high2float(ax);
    const float ay0 = __low2float(ay), ay1 = __high2float(ay);

    const float v = ay0 * (ax0 * p00 + ax1 * p01) +
                    ay1 * (ax0 * p10 + ax1 * p11);
    outc[sd.y] = v;
  }
}

extern "C" void kernel_launch(void* const* d_in, const int* in_sizes, int n_in,
                              void* d_out, int out_size, void* d_ws, size_t ws_size,
                              hipStream_t stream) {
  const float* feat = (const float*)d_in[0];
  const float* rois = (const float*)d_in[1];
  float* out = (float*)d_out;
  int* ws = (int*)d_ws;
  uint4* samples = (uint4*)((char*)d_ws + WS_SAMPLES_BYTE_OFF);

  const int K = in_sizes[1] / 5;  // 1024

  setup_kernel<<<1, 1024, 0, stream>>>(rois, K, ws);
  precompute_kernel<<<(K * OSP + 255) / 256, 256, 0, stream>>>(rois, ws, K,
                                                               samples);
  roi_align_main_kernel<<<FM_N * FM_C, MAIN_BLK, 0, stream>>>(feat, ws,
                                                              samples, out);
}

// Round 4
// 109.741 us; speedup vs baseline: 2.8071x; 1.2663x over previous
//
#include <hip/hip_runtime.h>
#include <hip/hip_fp16.h>

// RoI Align, ALIGNED=False, SCALE=160.
// feat: (N=8, C=256, H=160, W=160) fp32
// rois: (K=1024, 5) fp32 [b, x1, y1, x2, y2]
// out:  (K, C, 14, 14) fp32
//
// Structure:
//  A) setup_kernel: per-batch counts, batch-grouped slot per k, klist.
//  B) precompute_kernel: 8-byte sample descriptor per (k,s):
//     {o00|dx|dy|wy1_q13|vy0|vy1, ax(half2)} — weights computed once, not 256x.
//  C) main kernel: block = (b, channel-PAIR); stage both planes interleaved
//     as half2 in LDS (one ds_read_b32 serves 2 channels); iterate batch-b
//     samples; nontemporal dword stores.

#define FM_N 8
#define FM_C 256
#define FM_H 160
#define FM_W 160
#define PLANE (FM_H * FM_W)   // 25600
#define OH 14
#define OW 14
#define OSP (OH * OW)         // 196
#define KMAX 1024
#define SCALE_HW 160.0f
#define MAIN_BLK 1024

// ws layout (int32 units):
//   [0..7]      cnt[b]
//   [8..15]     koff[b] (exclusive prefix sum)
//   [16..16+KMAX) klist[slot] -> k   (batch-grouped)
//   byte 4224:  samples[K*196] as uint2
#define WS_KLIST_OFF 16
#define WS_SAMPLES_BYTE_OFF 4224

__global__ void setup_kernel(const float* __restrict__ rois, int K,
                             int* __restrict__ ws) {
  __shared__ int cnt[FM_N];
  __shared__ int koff[FM_N];
  const int t = threadIdx.x;
  if (t < FM_N) cnt[t] = 0;
  __syncthreads();
  int myb = -1, pos = 0;
  if (t < K) {
    myb = (int)rois[t * 5];
    pos = atomicAdd(&cnt[myb], 1);  // rank order irrelevant: each sample
                                    // writes a unique output location
  }
  __syncthreads();
  if (t == 0) {
    int acc = 0;
    for (int b = 0; b < FM_N; ++b) { koff[b] = acc; acc += cnt[b]; }
  }
  __syncthreads();
  if (t < K) {
    const int slot = koff[myb] + pos;
    ws[WS_KLIST_OFF + slot] = t;          // klist: slot -> k
  }
  if (t < FM_N) { ws[t] = cnt[t]; ws[FM_N + t] = koff[t]; }
}

__global__ __launch_bounds__(256) void precompute_kernel(
    const float* __restrict__ rois, const int* __restrict__ ws, int K,
    uint2* __restrict__ samples) {
  const int g = blockIdx.x * 256 + threadIdx.x;
  if (g >= K * OSP) return;
  const int slot = g / OSP;            // batch-grouped slot
  const int s = g - slot * OSP;
  const int k = ws[WS_KLIST_OFF + slot];

  const float x1 = rois[k * 5 + 1] * SCALE_HW;
  const float y1 = rois[k * 5 + 2] * SCALE_HW;
  const float x2 = rois[k * 5 + 3] * SCALE_HW;
  const float y2 = rois[k * 5 + 4] * SCALE_HW;

  const int oy = s / OW;
  const int ox = s - oy * OW;
  const float gx = (float)ox * (1.0f / (OW - 1));
  const float gy = (float)oy * (1.0f / (OH - 1));

  // ALIGNED=False index math collapses to ix = fx - 0.5
  const float ix = x1 + gx * (x2 - x1) - 0.5f;
  const float iy = y1 + gy * (y2 - y1) - 0.5f;

  const float fx0 = floorf(ix);
  const float fy0 = floorf(iy);
  const int x0 = (int)fx0;
  const int y0 = (int)fy0;
  const float wx1 = ix - fx0;
  const float wy1 = iy - fy0;

  const float vx0 = (x0 >= 0 && x0 < FM_W) ? 1.0f : 0.0f;
  const float vx1 = (x0 + 1 >= 0 && x0 + 1 < FM_W) ? 1.0f : 0.0f;
  const unsigned vy0 = (y0 >= 0 && y0 < FM_H) ? 1u : 0u;
  const unsigned vy1 = (y0 + 1 >= 0 && y0 + 1 < FM_H) ? 1u : 0u;

  const int x0c = min(max(x0, 0), FM_W - 1);
  const int x1c = min(max(x0 + 1, 0), FM_W - 1);
  const int y0c = min(max(y0, 0), FM_H - 1);
  const int y1c = min(max(y0 + 1, 0), FM_H - 1);

  const unsigned o00 = (unsigned)(y0c * FM_W + x0c);  // 15 bits
  const unsigned dx = (unsigned)(x1c - x0c);          // 0/1
  const unsigned dyr = (unsigned)(y1c - y0c);         // 0/1
  unsigned wq = (unsigned)(wy1 * 8192.0f + 0.5f);
  wq = wq > 8191u ? 8191u : wq;

  const __half2 axh = __floats2half2_rn((1.0f - wx1) * vx0, wx1 * vx1);

  uint2 sd;
  sd.x = o00 | (dx << 15) | (dyr << 16) | (wq << 17) | (vy0 << 30) | (vy1 << 31);
  sd.y = *(const unsigned*)&axh;
  samples[(size_t)slot * OSP + s] = sd;
}

__global__ __launch_bounds__(MAIN_BLK) void roi_align_main_kernel(
    const float* __restrict__ feat, const int* __restrict__ ws,
    const uint2* __restrict__ samples, float* __restrict__ out) {
  __shared__ __align__(16) __half2 plane[PLANE];  // lo = c0, hi = c1
  __shared__ int klist[KMAX];

  const int c0 = blockIdx.x * 2;
  const int b = blockIdx.y;
  const int t = threadIdx.x;

  const int cnt = ws[b];
  const int koff = ws[FM_N + b];

  // stage klist slice for this batch
  for (int i = t; i < cnt; i += MAIN_BLK)
    klist[i] = ws[WS_KLIST_OFF + koff + i];

  // stage planes c0, c1 interleaved as half2; one ds_write_b128 per float4 pair
  const float4* __restrict__ srcA =
      (const float4*)(feat + ((size_t)b * FM_C + c0) * PLANE);
  const float4* __restrict__ srcB = srcA + PLANE / 4;
  uint4* __restrict__ pl4 = (uint4*)plane;
  for (int i = t; i < PLANE / 4; i += MAIN_BLK) {
    const float4 a = srcA[i];
    const float4 bb = srcB[i];
    const __half2 h0 = __floats2half2_rn(a.x, bb.x);
    const __half2 h1 = __floats2half2_rn(a.y, bb.y);
    const __half2 h2 = __floats2half2_rn(a.z, bb.z);
    const __half2 h3 = __floats2half2_rn(a.w, bb.w);
    uint4 u;
    u.x = *(const unsigned*)&h0;
    u.y = *(const unsigned*)&h1;
    u.z = *(const unsigned*)&h2;
    u.w = *(const unsigned*)&h3;
    pl4[i] = u;
  }
  __syncthreads();

  const uint2* __restrict__ sam = samples + (size_t)koff * OSP;
  const int total = cnt * OSP;

#pragma unroll 2
  for (int w = t; w < total; w += MAIN_BLK) {
    const uint2 sd = sam[w];
    const unsigned kl = (unsigned)w / OSP;       // magic-mul div
    const int s = w - (int)kl * OSP;
    const int k = klist[kl];

    const int o00 = (int)(sd.x & 0x7FFFu);
    const int dx = (int)((sd.x >> 15) & 1u);
    const int o10 = o00 + (int)((sd.x >> 16) & 1u) * FM_W;

    const __half2 p00 = plane[o00];
    const __half2 p01 = plane[o00 + dx];
    const __half2 p10 = plane[o10];
    const __half2 p11 = plane[o10 + dx];

    const float wy1 = (float)((sd.x >> 17) & 0x1FFFu) * (1.0f / 8192.0f);
    const float ay0 = ((sd.x >> 30) & 1u) ? (1.0f - wy1) : 0.0f;
    const float ay1 = (sd.x >> 31) ? wy1 : 0.0f;
    const __half2 ax = *(const __half2*)&sd.y;
    const float ax0 = __low2float(ax), ax1 = __high2float(ax);

    const float vA = ay0 * (ax0 * __low2float(p00) + ax1 * __low2float(p01)) +
                     ay1 * (ax0 * __low2float(p10) + ax1 * __low2float(p11));
    const float vB = ay0 * (ax0 * __high2float(p00) + ax1 * __high2float(p01)) +
                     ay1 * (ax0 * __high2float(p10) + ax1 * __high2float(p11));

    const size_t ob = ((size_t)k * FM_C + c0) * OSP + s;
    __builtin_nontemporal_store(vA, &out[ob]);
    __builtin_nontemporal_store(vB, &out[ob + OSP]);
  }
}

extern "C" void kernel_launch(void* const* d_in, const int* in_sizes, int n_in,
                              void* d_out, int out_size, void* d_ws, size_t ws_size,
                              hipStream_t stream) {
  const float* feat = (const float*)d_in[0];
  const float* rois = (const float*)d_in[1];
  float* out = (float*)d_out;
  int* ws = (int*)d_ws;
  uint2* samples = (uint2*)((char*)d_ws + WS_SAMPLES_BYTE_OFF);

  const int K = in_sizes[1] / 5;  // 1024

  setup_kernel<<<1, 1024, 0, stream>>>(rois, K, ws);
  precompute_kernel<<<(K * OSP + 255) / 256, 256, 0, stream>>>(rois, ws, K,
                                                               samples);
  roi_align_main_kernel<<<dim3(FM_C / 2, FM_N), MAIN_BLK, 0, stream>>>(
      feat, ws, samples, out);
}

// Round 5
// 100.709 us; speedup vs baseline: 3.0589x; 1.0897x over previous
//
#include <hip/hip_runtime.h>
#include <hip/hip_fp16.h>

// RoI Align, ALIGNED=False, SCALE=160.
// feat: (N=8, C=256, H=160, W=160) fp32
// rois: (K=1024, 5) fp32 [b, x1, y1, x2, y2]
// out:  (K, C, 14, 14) fp32
//
// Structure:
//  A) setup_kernel: per-batch counts, batch-grouped klist.
//  B) precompute_kernel: 8-byte sample descriptor per (k,s) — weights
//     computed once, not 256x.
//  C) main kernel: block = (b, 2 channel-PAIRS). For each pair, both planes
//     staged interleaved as half2 in LDS (one ds_read_b32 serves 2 channels).
//     Next pair's global loads are issued BEFORE the current pair's compute
//     (async-STAGE split) so HBM fetch hides under gather+store.

#define FM_N 8
#define FM_C 256
#define FM_H 160
#define FM_W 160
#define PLANE (FM_H * FM_W)   // 25600
#define PLANE4 (PLANE / 4)    // 6400 float4 per plane
#define OH 14
#define OW 14
#define OSP (OH * OW)         // 196
#define KMAX 1024
#define SCALE_HW 160.0f
#define MAIN_BLK 1024
#define NCP 2                 // channel-pairs per block (4 channels)
#define STG_IT 7              // ceil(PLANE4 / MAIN_BLK)

typedef float f4 __attribute__((ext_vector_type(4)));

// ws layout (int32 units):
//   [0..7]      cnt[b]
//   [8..15]     koff[b] (exclusive prefix sum)
//   [16..16+KMAX) klist[slot] -> k   (batch-grouped)
//   byte 4224:  samples[K*196] as uint2
#define WS_KLIST_OFF 16
#define WS_SAMPLES_BYTE_OFF 4224

__global__ void setup_kernel(const float* __restrict__ rois, int K,
                             int* __restrict__ ws) {
  __shared__ int cnt[FM_N];
  __shared__ int koff[FM_N];
  const int t = threadIdx.x;
  if (t < FM_N) cnt[t] = 0;
  __syncthreads();
  int myb = -1, pos = 0;
  if (t < K) {
    myb = (int)rois[t * 5];
    pos = atomicAdd(&cnt[myb], 1);  // rank order irrelevant: each sample
                                    // writes a unique output location
  }
  __syncthreads();
  if (t == 0) {
    int acc = 0;
    for (int b = 0; b < FM_N; ++b) { koff[b] = acc; acc += cnt[b]; }
  }
  __syncthreads();
  if (t < K) ws[WS_KLIST_OFF + koff[myb] + pos] = t;
  if (t < FM_N) { ws[t] = cnt[t]; ws[FM_N + t] = koff[t]; }
}

__global__ __launch_bounds__(256) void precompute_kernel(
    const float* __restrict__ rois, const int* __restrict__ ws, int K,
    uint2* __restrict__ samples) {
  const int g = blockIdx.x * 256 + threadIdx.x;
  if (g >= K * OSP) return;
  const int slot = g / OSP;            // batch-grouped slot
  const int s = g - slot * OSP;
  const int k = ws[WS_KLIST_OFF + slot];

  const float x1 = rois[k * 5 + 1] * SCALE_HW;
  const float y1 = rois[k * 5 + 2] * SCALE_HW;
  const float x2 = rois[k * 5 + 3] * SCALE_HW;
  const float y2 = rois[k * 5 + 4] * SCALE_HW;

  const int oy = s / OW;
  const int ox = s - oy * OW;
  const float gx = (float)ox * (1.0f / (OW - 1));
  const float gy = (float)oy * (1.0f / (OH - 1));

  // ALIGNED=False index math collapses to ix = fx - 0.5
  const float ix = x1 + gx * (x2 - x1) - 0.5f;
  const float iy = y1 + gy * (y2 - y1) - 0.5f;

  const float fx0 = floorf(ix);
  const float fy0 = floorf(iy);
  const int x0 = (int)fx0;
  const int y0 = (int)fy0;
  const float wx1 = ix - fx0;
  const float wy1 = iy - fy0;

  const float vx0 = (x0 >= 0 && x0 < FM_W) ? 1.0f : 0.0f;
  const float vx1 = (x0 + 1 >= 0 && x0 + 1 < FM_W) ? 1.0f : 0.0f;
  const unsigned vy0 = (y0 >= 0 && y0 < FM_H) ? 1u : 0u;
  const unsigned vy1 = (y0 + 1 >= 0 && y0 + 1 < FM_H) ? 1u : 0u;

  const int x0c = min(max(x0, 0), FM_W - 1);
  const int x1c = min(max(x0 + 1, 0), FM_W - 1);
  const int y0c = min(max(y0, 0), FM_H - 1);
  const int y1c = min(max(y0 + 1, 0), FM_H - 1);

  const unsigned o00 = (unsigned)(y0c * FM_W + x0c);  // 15 bits
  const unsigned dx = (unsigned)(x1c - x0c);          // 0/1
  const unsigned dyr = (unsigned)(y1c - y0c);         // 0/1
  unsigned wq = (unsigned)(wy1 * 8192.0f + 0.5f);
  wq = wq > 8191u ? 8191u : wq;

  const __half2 axh = __floats2half2_rn((1.0f - wx1) * vx0, wx1 * vx1);

  uint2 sd;
  sd.x = o00 | (dx << 15) | (dyr << 16) | (wq << 17) | (vy0 << 30) | (vy1 << 31);
  sd.y = *(const unsigned*)&axh;
  samples[(size_t)slot * OSP + s] = sd;
}

__global__ __launch_bounds__(MAIN_BLK) void roi_align_main_kernel(
    const float* __restrict__ feat, const int* __restrict__ ws,
    const uint2* __restrict__ samples, float* __restrict__ out) {
  __shared__ __align__(16) __half2 plane[PLANE];  // lo = c0, hi = c0+1
  __shared__ int klist[KMAX];

  const int b = blockIdx.y;
  const int p0 = blockIdx.x * NCP;  // first channel-pair index
  const int t = threadIdx.x;

  const int cnt = ws[b];
  const int koff = ws[FM_N + b];
  for (int i = t; i < cnt; i += MAIN_BLK)
    klist[i] = ws[WS_KLIST_OFF + koff + i];

  const uint2* __restrict__ sam = samples + (size_t)koff * OSP;
  const int total = cnt * OSP;
  const f4* __restrict__ fbase =
      (const f4*)feat + (size_t)b * FM_C * PLANE4;

  f4 ra[STG_IT], rb[STG_IT];

  // issue global loads for pair p into ra/rb (plane A and B are contiguous)
  auto load_pair = [&](int p) {
    const f4* __restrict__ srcA = fbase + (size_t)(2 * p) * PLANE4;
    const f4* __restrict__ srcB = srcA + PLANE4;
#pragma unroll
    for (int i = 0; i < STG_IT; ++i) {
      const int idx = t + i * MAIN_BLK;
      if (idx < PLANE4) {
        ra[i] = __builtin_nontemporal_load(&srcA[idx]);
        rb[i] = __builtin_nontemporal_load(&srcB[idx]);
      }
    }
  };

  // convert staged regs to interleaved half2 and write LDS
  auto write_plane = [&]() {
    uint4* __restrict__ pl4 = (uint4*)plane;
#pragma unroll
    for (int i = 0; i < STG_IT; ++i) {
      const int idx = t + i * MAIN_BLK;
      if (idx < PLANE4) {
        const __half2 h0 = __floats2half2_rn(ra[i].x, rb[i].x);
        const __half2 h1 = __floats2half2_rn(ra[i].y, rb[i].y);
        const __half2 h2 = __floats2half2_rn(ra[i].z, rb[i].z);
        const __half2 h3 = __floats2half2_rn(ra[i].w, rb[i].w);
        uint4 u;
        u.x = *(const unsigned*)&h0;
        u.y = *(const unsigned*)&h1;
        u.z = *(const unsigned*)&h2;
        u.w = *(const unsigned*)&h3;
        pl4[idx] = u;
      }
    }
  };

  auto compute_pair = [&](int c0) {
#pragma unroll 2
    for (int w = t; w < total; w += MAIN_BLK) {
      const uint2 sd = sam[w];
      const unsigned kl = (unsigned)w / OSP;  // magic-mul div
      const int s = w - (int)kl * OSP;
      const int k = klist[kl];

      const int o00 = (int)(sd.x & 0x7FFFu);
      const int dx = (int)((sd.x >> 15) & 1u);
      const int o10 = o00 + (int)((sd.x >> 16) & 1u) * FM_W;

      const __half2 p00 = plane[o00];
      const __half2 p01 = plane[o00 + dx];
      const __half2 p10 = plane[o10];
      const __half2 p11 = plane[o10 + dx];

      const float wy1 = (float)((sd.x >> 17) & 0x1FFFu) * (1.0f / 8192.0f);
      const float ay0 = ((sd.x >> 30) & 1u) ? (1.0f - wy1) : 0.0f;
      const float ay1 = (sd.x >> 31) ? wy1 : 0.0f;
      const __half2 ax = *(const __half2*)&sd.y;
      const float ax0 = __low2float(ax), ax1 = __high2float(ax);

      const float vA = ay0 * (ax0 * __low2float(p00) + ax1 * __low2float(p01)) +
                       ay1 * (ax0 * __low2float(p10) + ax1 * __low2float(p11));
      const float vB = ay0 * (ax0 * __high2float(p00) + ax1 * __high2float(p01)) +
                       ay1 * (ax0 * __high2float(p10) + ax1 * __high2float(p11));

      const size_t ob = ((size_t)k * FM_C + c0) * OSP + s;
      out[ob] = vA;
      out[ob + OSP] = vB;
    }
  };

  // prologue: stage pair p0
  load_pair(p0);
  write_plane();
  __syncthreads();

  for (int cp = 0; cp < NCP; ++cp) {
    if (cp + 1 < NCP) load_pair(p0 + cp + 1);  // in flight during compute
    compute_pair(2 * (p0 + cp));
    if (cp + 1 < NCP) {
      __syncthreads();   // everyone done reading current plane
      write_plane();     // vmcnt wait happens here, after compute
      __syncthreads();   // new plane visible
    }
  }
}

extern "C" void kernel_launch(void* const* d_in, const int* in_sizes, int n_in,
                              void* d_out, int out_size, void* d_ws, size_t ws_size,
                              hipStream_t stream) {
  const float* feat = (const float*)d_in[0];
  const float* rois = (const float*)d_in[1];
  float* out = (float*)d_out;
  int* ws = (int*)d_ws;
  uint2* samples = (uint2*)((char*)d_ws + WS_SAMPLES_BYTE_OFF);

  const int K = in_sizes[1] / 5;  // 1024

  setup_kernel<<<1, 1024, 0, stream>>>(rois, K, ws);
  precompute_kernel<<<(K * OSP + 255) / 256, 256, 0, stream>>>(rois, ws, K,
                                                               samples);
  roi_align_main_kernel<<<dim3(FM_C / 2 / NCP, FM_N), MAIN_BLK, 0, stream>>>(
      feat, ws, samples, out);
}

// Round 6
// 98.741 us; speedup vs baseline: 3.1198x; 1.0199x over previous
//
#include <hip/hip_runtime.h>
#include <hip/hip_fp16.h>

// RoI Align, ALIGNED=False, SCALE=160.
// feat: (N=8, C=256, H=160, W=160) fp32
// rois: (K=1024, 5) fp32 [b, x1, y1, x2, y2]
// out:  (K, C, 14, 14) fp32
//
// Structure:
//  A) setup_kernel: per-batch counts, batch-grouped klist.
//  B) precompute_kernel: 8-byte descriptor per (k,s): left-base index bx
//     (x-corners are ALWAYS plane[bx], plane[bx+1]; border cases folded into
//     zero ax weights), row step, quantized wy, y-valid bits, ax as half2.
//  C) main kernel: block = (b, 2 channel-PAIRS). Planes staged interleaved as
//     half2 in LDS (one ds_read2_b32 serves 2 channels x 2 corners). Next
//     pair's global loads issued before current pair's compute (async-STAGE).

#define FM_N 8
#define FM_C 256
#define FM_H 160
#define FM_W 160
#define PLANE (FM_H * FM_W)   // 25600
#define PLANE4 (PLANE / 4)    // 6400 float4 per plane
#define OH 14
#define OW 14
#define OSP (OH * OW)         // 196
#define KMAX 1024
#define SCALE_HW 160.0f
#define MAIN_BLK 1024
#define NCP 2                 // channel-pairs per block (4 channels)
#define STG_IT 7              // ceil(PLANE4 / MAIN_BLK)

typedef float f4 __attribute__((ext_vector_type(4)));

// ws layout (int32 units):
//   [0..7]      cnt[b]
//   [8..15]     koff[b] (exclusive prefix sum)
//   [16..16+KMAX) klist[slot] -> k   (batch-grouped)
//   byte 4224:  samples[K*196] as uint2
#define WS_KLIST_OFF 16
#define WS_SAMPLES_BYTE_OFF 4224

__global__ void setup_kernel(const float* __restrict__ rois, int K,
                             int* __restrict__ ws) {
  __shared__ int cnt[FM_N];
  __shared__ int koff[FM_N];
  const int t = threadIdx.x;
  if (t < FM_N) cnt[t] = 0;
  __syncthreads();
  int myb = -1, pos = 0;
  if (t < K) {
    myb = (int)rois[t * 5];
    pos = atomicAdd(&cnt[myb], 1);  // rank order irrelevant: each sample
                                    // writes a unique output location
  }
  __syncthreads();
  if (t == 0) {
    int acc = 0;
    for (int b = 0; b < FM_N; ++b) { koff[b] = acc; acc += cnt[b]; }
  }
  __syncthreads();
  if (t < K) ws[WS_KLIST_OFF + koff[myb] + pos] = t;
  if (t < FM_N) { ws[t] = cnt[t]; ws[FM_N + t] = koff[t]; }
}

__global__ __launch_bounds__(256) void precompute_kernel(
    const float* __restrict__ rois, const int* __restrict__ ws, int K,
    uint2* __restrict__ samples) {
  const int g = blockIdx.x * 256 + threadIdx.x;
  if (g >= K * OSP) return;
  const int slot = g / OSP;            // batch-grouped slot
  const int s = g - slot * OSP;
  const int k = ws[WS_KLIST_OFF + slot];

  const float x1 = rois[k * 5 + 1] * SCALE_HW;
  const float y1 = rois[k * 5 + 2] * SCALE_HW;
  const float x2 = rois[k * 5 + 3] * SCALE_HW;
  const float y2 = rois[k * 5 + 4] * SCALE_HW;

  const int oy = s / OW;
  const int ox = s - oy * OW;
  const float gx = (float)ox * (1.0f / (OW - 1));
  const float gy = (float)oy * (1.0f / (OH - 1));

  // ALIGNED=False index math collapses to ix = fx - 0.5
  const float ix = x1 + gx * (x2 - x1) - 0.5f;
  const float iy = y1 + gy * (y2 - y1) - 0.5f;

  const float fx0 = floorf(ix);
  const float fy0 = floorf(iy);
  const int x0 = (int)fx0;
  const int y0 = (int)fy0;
  const float wx1 = ix - fx0;
  const float wy1 = iy - fy0;

  const bool vx0 = (x0 >= 0 && x0 < FM_W);
  const bool vx1 = (x0 + 1 >= 0 && x0 + 1 < FM_W);
  const unsigned vy0 = (y0 >= 0 && y0 < FM_H) ? 1u : 0u;
  const unsigned vy1 = (y0 + 1 >= 0 && y0 + 1 < FM_H) ? 1u : 0u;

  const int x0c = min(max(x0, 0), FM_W - 1);
  const int x1c = min(max(x0 + 1, 0), FM_W - 1);
  const int y0c = min(max(y0, 0), FM_H - 1);
  const int y1c = min(max(y0 + 1, 0), FM_H - 1);

  const int o00 = y0c * FM_W + x0c;
  const int o01 = y0c * FM_W + x1c;
  // Left-base: corners are always {plane[bx], plane[bx+1]}.
  //  interior:          bx = o00          (o01 = o00+1)
  //  left border  vx0=0: bx = o01-1       (left slot garbage, ax0 == 0)
  //  right border vx1=0: bx = o00         (right slot garbage, ax1 == 0)
  const int bx = vx1 ? (o01 - 1) : o00;   // in [-1, 25599]
  const unsigned bxs = (unsigned)(bx + 4);  // +4-entry front pad; 15 bits
  const unsigned dyr = (unsigned)(y1c - y0c);  // 0/1
  unsigned wq = (unsigned)(wy1 * 8192.0f + 0.5f);
  wq = wq > 8191u ? 8191u : wq;

  const __half2 axh = __floats2half2_rn((1.0f - wx1) * (vx0 ? 1.0f : 0.0f),
                                        wx1 * (vx1 ? 1.0f : 0.0f));

  uint2 sd;
  sd.x = bxs | (dyr << 15) | (wq << 16) | (vy0 << 29) | (vy1 << 30);
  sd.y = *(const unsigned*)&axh;
  samples[(size_t)slot * OSP + s] = sd;
}

__global__ __launch_bounds__(MAIN_BLK) void roi_align_main_kernel(
    const float* __restrict__ feat, const int* __restrict__ ws,
    const uint2* __restrict__ samples, float* __restrict__ out) {
  // 4 front pad + plane + 4 back pad (pads zeroed; reads with weight 0 may
  // land there or on neighboring real pixels — always finite).
  __shared__ __align__(16) __half2 planeBuf[PLANE + 8];
  __shared__ int klist[KMAX];  // precomputed k*FM_C*OSP output bases

  const int b = blockIdx.y;
  const int p0 = blockIdx.x * NCP;  // first channel-pair index
  const int t = threadIdx.x;

  const int cnt = ws[b];
  const int koff = ws[FM_N + b];
  for (int i = t; i < cnt; i += MAIN_BLK)
    klist[i] = ws[WS_KLIST_OFF + koff + i] * (FM_C * OSP);
  if (t < 4) {
    planeBuf[t] = __floats2half2_rn(0.0f, 0.0f);
    planeBuf[PLANE + 4 + t] = __floats2half2_rn(0.0f, 0.0f);
  }

  const uint2* __restrict__ sam = samples + (size_t)koff * OSP;
  const int total = cnt * OSP;
  const f4* __restrict__ fbase = (const f4*)feat + (size_t)b * FM_C * PLANE4;
  __half2* __restrict__ planeP = planeBuf + 4;

  f4 ra[STG_IT], rb[STG_IT];

  auto load_pair = [&](int p) {
    const f4* __restrict__ srcA = fbase + (size_t)(2 * p) * PLANE4;
    const f4* __restrict__ srcB = srcA + PLANE4;
#pragma unroll
    for (int i = 0; i < STG_IT; ++i) {
      const int idx = t + i * MAIN_BLK;
      if (idx < PLANE4) {
        ra[i] = __builtin_nontemporal_load(&srcA[idx]);
        rb[i] = __builtin_nontemporal_load(&srcB[idx]);
      }
    }
  };

  auto write_plane = [&]() {
    uint4* __restrict__ pl4 = (uint4*)planeP;
#pragma unroll
    for (int i = 0; i < STG_IT; ++i) {
      const int idx = t + i * MAIN_BLK;
      if (idx < PLANE4) {
        const __half2 h0 = __floats2half2_rn(ra[i].x, rb[i].x);
        const __half2 h1 = __floats2half2_rn(ra[i].y, rb[i].y);
        const __half2 h2 = __floats2half2_rn(ra[i].z, rb[i].z);
        const __half2 h3 = __floats2half2_rn(ra[i].w, rb[i].w);
        uint4 u;
        u.x = *(const unsigned*)&h0;
        u.y = *(const unsigned*)&h1;
        u.z = *(const unsigned*)&h2;
        u.w = *(const unsigned*)&h3;
        pl4[idx] = u;
      }
    }
  };

  auto compute_pair = [&](int c0) {
    float* __restrict__ outc = out + (size_t)c0 * OSP;
#pragma unroll 4
    for (int w = t; w < total; w += MAIN_BLK) {
      const uint2 sd = sam[w];
      const unsigned kl = (unsigned)w / OSP;  // magic-mul div
      const int s = w - (int)kl * OSP;
      const int kbase = klist[kl];

      const int bxs = (int)(sd.x & 0x7FFFu);
      const int b2 = bxs + (int)((sd.x >> 15) & 1u) * FM_W;

      // adjacent-pair LDS reads -> ds_read2_b32 (2 instrs for 4 corners,
      // each __half2 carries both channels)
      const __half2 pL0 = planeP[bxs - 4];   // == planeBuf[bxs]
      const __half2 pR0 = planeP[bxs - 3];
      const __half2 pL1 = planeP[b2 - 4];
      const __half2 pR1 = planeP[b2 - 3];

      const __half2 ax = *(const __half2*)&sd.y;
      const __half2 axl = __half2half2(__low2half(ax));
      const __half2 axr = __half2half2(__high2half(ax));
      const __half2 hx0 = __hfma2(pR0, axr, __hmul2(pL0, axl));
      const __half2 hx1 = __hfma2(pR1, axr, __hmul2(pL1, axl));

      const float wy1 = (float)((sd.x >> 16) & 0x1FFFu) * (1.0f / 8192.0f);
      const float ay0 = ((sd.x >> 29) & 1u) ? (1.0f - wy1) : 0.0f;
      const float ay1 = ((sd.x >> 30) & 1u) ? wy1 : 0.0f;

      const float vA = ay0 * __low2float(hx0) + ay1 * __low2float(hx1);
      const float vB = ay0 * __high2float(hx0) + ay1 * __high2float(hx1);

      const size_t ob = (size_t)(kbase + s);
      outc[ob] = vA;
      outc[ob + OSP] = vB;
    }
  };

  // prologue: stage pair p0
  load_pair(p0);
  write_plane();
  __syncthreads();

  for (int cp = 0; cp < NCP; ++cp) {
    if (cp + 1 < NCP) load_pair(p0 + cp + 1);  // in flight during compute
    compute_pair(2 * (p0 + cp));
    if (cp + 1 < NCP) {
      __syncthreads();   // everyone done reading current plane
      write_plane();     // vmcnt wait happens here, after compute
      __syncthreads();   // new plane visible
    }
  }
}

extern "C" void kernel_launch(void* const* d_in, const int* in_sizes, int n_in,
                              void* d_out, int out_size, void* d_ws, size_t ws_size,
                              hipStream_t stream) {
  const float* feat = (const float*)d_in[0];
  const float* rois = (const float*)d_in[1];
  float* out = (float*)d_out;
  int* ws = (int*)d_ws;
  uint2* samples = (uint2*)((char*)d_ws + WS_SAMPLES_BYTE_OFF);

  const int K = in_sizes[1] / 5;  // 1024

  setup_kernel<<<1, 1024, 0, stream>>>(rois, K, ws);
  precompute_kernel<<<(K * OSP + 255) / 256, 256, 0, stream>>>(rois, ws, K,
                                                               samples);
  roi_align_main_kernel<<<dim3(FM_C / 2 / NCP, FM_N), MAIN_BLK, 0, stream>>>(
      feat, ws, samples, out);
}